// Round 4
// baseline (171.685 us; speedup 1.0000x reference)
//
#include <hip/hip_runtime.h>

#define NIMG 16
#define H 512
#define W 512
#define CH 256
#define CW 256
#define HALF 7   // PATCH=15

// bf16 helpers (RNE), bit-level to avoid API surprises; values are finite.
static __device__ __forceinline__ unsigned short f2bf(float f) {
    unsigned u = __float_as_uint(f);
    u += 0x7FFFu + ((u >> 16) & 1u);
    return (unsigned short)(u >> 16);
}
static __device__ __forceinline__ float bf2f(unsigned short h) {
    return __uint_as_float(((unsigned)h) << 16);
}

// ---------------------------------------------------------------------------
// K1: fused diff + horizontal 15-tap box. One block (256 thr) per (n, cy)
// full-res row pair. dY rows + pooled dU/dV row live only in LDS (zero-padded
// +-8: no clamping). Outputs hY (bf16, 8 MB) and hUV (bf16, 4 MB).
// ---------------------------------------------------------------------------
__global__ void diff_hbox_kernel(const float* __restrict__ in, const float* __restrict__ tgt,
                                 unsigned short* __restrict__ hY,
                                 unsigned short* __restrict__ hUV) {
    __shared__ float sY0[W + 16], sY1[W + 16], sU[CW + 16], sV[CW + 16];
    const int tid = threadIdx.x;
    const int cy = blockIdx.x & (CH - 1);
    const int n  = blockIdx.x >> 8;

    if (tid < 8) {
        sY0[tid] = 0.f; sY0[W + 8 + tid] = 0.f;
        sY1[tid] = 0.f; sY1[W + 8 + tid] = 0.f;
        sU[tid] = 0.f;  sU[CW + 8 + tid] = 0.f;
        sV[tid] = 0.f;  sV[CW + 8 + tid] = 0.f;
    }

    const size_t plane = (size_t)H * W;
    const float* pi = in  + (size_t)n * 3 * plane;
    const float* pt = tgt + (size_t)n * 3 * plane;

    const int y0 = cy << 1;
    const int x0 = tid << 1;
    const size_t o0 = (size_t)y0 * W + x0;
    const size_t o1 = o0 + W;

    float2 ir0 = *(const float2*)(pi + o0);
    float2 ir1 = *(const float2*)(pi + o1);
    float2 ig0 = *(const float2*)(pi + plane + o0);
    float2 ig1 = *(const float2*)(pi + plane + o1);
    float2 ib0 = *(const float2*)(pi + 2 * plane + o0);
    float2 ib1 = *(const float2*)(pi + 2 * plane + o1);

    float2 tr0 = *(const float2*)(pt + o0);
    float2 tr1 = *(const float2*)(pt + o1);
    float2 tg0 = *(const float2*)(pt + plane + o0);
    float2 tg1 = *(const float2*)(pt + plane + o1);
    float2 tb0 = *(const float2*)(pt + 2 * plane + o0);
    float2 tb1 = *(const float2*)(pt + 2 * plane + o1);

    float dr00 = ir0.x - tr0.x, dr01 = ir0.y - tr0.y;
    float dr10 = ir1.x - tr1.x, dr11 = ir1.y - tr1.y;
    float dg00 = ig0.x - tg0.x, dg01 = ig0.y - tg0.y;
    float dg10 = ig1.x - tg1.x, dg11 = ig1.y - tg1.y;
    float db00 = ib0.x - tb0.x, db01 = ib0.y - tb0.y;
    float db10 = ib1.x - tb1.x, db11 = ib1.y - tb1.y;

    sY0[8 + x0]     = 0.299f * dr00 + 0.587f * dg00 + 0.114f * db00;
    sY0[8 + x0 + 1] = 0.299f * dr01 + 0.587f * dg01 + 0.114f * db01;
    sY1[8 + x0]     = 0.299f * dr10 + 0.587f * dg10 + 0.114f * db10;
    sY1[8 + x0 + 1] = 0.299f * dr11 + 0.587f * dg11 + 0.114f * db11;

    float sr = dr00 + dr01 + dr10 + dr11;
    float sg = dg00 + dg01 + dg10 + dg11;
    float sb = db00 + db01 + db10 + db11;
    sU[8 + tid] = (-0.169f * sr - 0.331f * sg + 0.5f * sb) * 0.25f;
    sV[8 + tid] = ( 0.5f   * sr - 0.46f  * sg - 0.04f * sb) * 0.25f;

    __syncthreads();

    // --- hbox Y: each thread 4 consecutive outputs in one row (running sum) ---
    {
        const int row = tid >> 7;              // 0 or 1
        const int xb  = (tid & 127) << 2;      // 0..508
        const float* srow = row ? sY1 : sY0;
        float s = 0.f;
#pragma unroll
        for (int j = 1; j <= 15; ++j) s += srow[xb + j];
        ushort4 o;
        o.x = f2bf(s); s += srow[xb + 16] - srow[xb + 1];
        o.y = f2bf(s); s += srow[xb + 17] - srow[xb + 2];
        o.z = f2bf(s); s += srow[xb + 18] - srow[xb + 3];
        o.w = f2bf(s);
        *(ushort4*)(hY + ((size_t)n * H + y0 + row) * W + xb) = o;
    }

    // --- hbox chroma: threads 0-127 -> U, 128-255 -> V, 2 outputs each ---
    {
        const int uv = tid >> 7;
        const int t  = tid & 127;
        const int xb = t << 1;
        const float* srow = uv ? sV : sU;
        float s = 0.f;
#pragma unroll
        for (int j = 1; j <= 15; ++j) s += srow[xb + j];
        ushort2 o;
        o.x = f2bf(s); s += srow[xb + 16] - srow[xb + 1];
        o.y = f2bf(s);
        const size_t p = (size_t)(n * 2 + uv);
        *(ushort2*)(hUV + (p * CH + cy) * CW + xb) = o;
    }
}

// ---------------------------------------------------------------------------
// K2: sliding-window vertical 15-tap box + square + block partial + last-block
// final reduce. 192 blocks: b<128 -> Y (img=b>>3, strip=(b>>2)&1, chunk=b&3,
// 128 rows each), else UV (plane=(b-128)>>1, chunk=(b-128)&1, 128 rows each).
// ---------------------------------------------------------------------------
#define NBLK 192
__global__ void vbox_finish_kernel(const unsigned short* __restrict__ hY,
                                   const unsigned short* __restrict__ hUV,
                                   float invY, float invC,
                                   float* __restrict__ partials,
                                   unsigned* __restrict__ counter,
                                   float* __restrict__ out) {
    const int b = blockIdx.x;
    float acc = 0.f;
    if (b < 128) {
        const int img   = b >> 3;
        const int strip = (b >> 2) & 1;
        const int chunk = b & 3;
        const int x = (strip << 8) + threadIdx.x;            // 0..511
        const unsigned short* col = hY + ((size_t)img << 18) + x;
        const int y0 = chunk << 7;
        float s = 0.f;
#pragma unroll
        for (int t = -HALF; t <= HALF; ++t) {
            int yy = y0 + t;
            s += ((unsigned)yy < (unsigned)H) ? bf2f(col[yy << 9]) : 0.f;
        }
        for (int i = 0; i < 128; ++i) {
            const int y = y0 + i;
            acc += s * s;
            const int ya = y + HALF + 1, yr = y - HALF;
            float va = ((unsigned)ya < (unsigned)H) ? bf2f(col[ya << 9]) : 0.f;
            float vr = ((unsigned)yr < (unsigned)H) ? bf2f(col[yr << 9]) : 0.f;
            s += va - vr;
        }
        acc *= invY;
    } else {
        const int bb = b - 128;
        const int plane = bb >> 1;
        const int chunk = bb & 1;
        const int x = threadIdx.x;                           // 0..255
        const unsigned short* col = hUV + ((size_t)plane << 16) + x;
        const int y0 = chunk << 7;
        float s = 0.f;
#pragma unroll
        for (int t = -HALF; t <= HALF; ++t) {
            int yy = y0 + t;
            s += ((unsigned)yy < (unsigned)CH) ? bf2f(col[yy << 8]) : 0.f;
        }
        for (int i = 0; i < 128; ++i) {
            const int y = y0 + i;
            acc += s * s;
            const int ya = y + HALF + 1, yr = y - HALF;
            float va = ((unsigned)ya < (unsigned)CH) ? bf2f(col[ya << 8]) : 0.f;
            float vr = ((unsigned)yr < (unsigned)CH) ? bf2f(col[yr << 8]) : 0.f;
            s += va - vr;
        }
        acc *= invC;
    }

    for (int o = 32; o > 0; o >>= 1) acc += __shfl_down(acc, o, 64);
    __shared__ float part[4];
    __shared__ bool amLast;
    const int lane = threadIdx.x & 63, wid = threadIdx.x >> 6;
    if (lane == 0) part[wid] = acc;
    __syncthreads();
    if (threadIdx.x == 0) {
        partials[b] = part[0] + part[1] + part[2] + part[3];
        __threadfence();                       // release: partial visible device-wide
        unsigned prev = atomicAdd(counter, 1u);
        amLast = (prev == NBLK - 1);
    }
    __syncthreads();
    if (amLast) {
        __threadfence();                       // acquire: see all partials
        float s = (threadIdx.x < NBLK) ? partials[threadIdx.x] : 0.f;
        for (int o = 32; o > 0; o >>= 1) s += __shfl_down(s, o, 64);
        __syncthreads();                       // part[] reuse
        if (lane == 0) part[wid] = s;
        __syncthreads();
        if (threadIdx.x == 0) *out = part[0] + part[1] + part[2] + part[3];
    }
}

extern "C" void kernel_launch(void* const* d_in, const int* in_sizes, int n_in,
                              void* d_out, int out_size, void* d_ws, size_t ws_size,
                              hipStream_t stream) {
    const float* input  = (const float*)d_in[0];
    const float* target = (const float*)d_in[1];
    float* out = (float*)d_out;

    const size_t yElems = (size_t)NIMG * H * W;      // 4,194,304
    const size_t cElems = (size_t)NIMG * CH * CW;    // 1,048,576

    unsigned short* hY  = (unsigned short*)d_ws;          // yElems bf16
    unsigned short* hUV = hY + yElems;                    // 2*cElems bf16
    float* partials = (float*)(hUV + 2 * cElems);         // NBLK floats
    unsigned* counter = (unsigned*)(partials + NBLK);     // 1 uint

    hipMemsetAsync(counter, 0, sizeof(unsigned), stream);

    diff_hbox_kernel<<<NIMG * CH, 256, 0, stream>>>(input, target, hY, hUV);

    vbox_finish_kernel<<<NBLK, 256, 0, stream>>>(
        hY, hUV, 1.0f / (float)yElems, 1.0f / (float)cElems,
        partials, counter, out);
}

// Round 5
// 135.851 us; speedup vs baseline: 1.2638x; 1.2638x over previous
//
#include <hip/hip_runtime.h>

#define NIMG 16
#define H 512
#define W 512
#define CH 256
#define CW 256
#define HALF 7   // PATCH=15

// bf16 helpers (RNE), bit-level.
static __device__ __forceinline__ unsigned short f2bf(float f) {
    unsigned u = __float_as_uint(f);
    u += 0x7FFFu + ((u >> 16) & 1u);
    return (unsigned short)(u >> 16);
}
static __device__ __forceinline__ float bf2f(unsigned short h) {
    return __uint_as_float(((unsigned)h) << 16);
}

// ---------------------------------------------------------------------------
// K1: fused diff + horizontal 15-tap box. One block (256 thr) per (n, cy)
// full-res row pair. dY rows + pooled dU/dV row live only in LDS (zero-padded
// +-8: no clamping). Outputs hY (bf16, 8 MB) and hUV (bf16, 4 MB).
// Compulsory-read-bound: 128 MB in, 12 MB out.
// ---------------------------------------------------------------------------
__global__ void diff_hbox_kernel(const float* __restrict__ in, const float* __restrict__ tgt,
                                 unsigned short* __restrict__ hY,
                                 unsigned short* __restrict__ hUV) {
    __shared__ float sY0[W + 16], sY1[W + 16], sU[CW + 16], sV[CW + 16];
    const int tid = threadIdx.x;
    const int cy = blockIdx.x & (CH - 1);
    const int n  = blockIdx.x >> 8;

    if (tid < 8) {
        sY0[tid] = 0.f; sY0[W + 8 + tid] = 0.f;
        sY1[tid] = 0.f; sY1[W + 8 + tid] = 0.f;
        sU[tid] = 0.f;  sU[CW + 8 + tid] = 0.f;
        sV[tid] = 0.f;  sV[CW + 8 + tid] = 0.f;
    }

    const size_t plane = (size_t)H * W;
    const float* pi = in  + (size_t)n * 3 * plane;
    const float* pt = tgt + (size_t)n * 3 * plane;

    const int y0 = cy << 1;
    const int x0 = tid << 1;
    const size_t o0 = (size_t)y0 * W + x0;
    const size_t o1 = o0 + W;

    float2 ir0 = *(const float2*)(pi + o0);
    float2 ir1 = *(const float2*)(pi + o1);
    float2 ig0 = *(const float2*)(pi + plane + o0);
    float2 ig1 = *(const float2*)(pi + plane + o1);
    float2 ib0 = *(const float2*)(pi + 2 * plane + o0);
    float2 ib1 = *(const float2*)(pi + 2 * plane + o1);

    float2 tr0 = *(const float2*)(pt + o0);
    float2 tr1 = *(const float2*)(pt + o1);
    float2 tg0 = *(const float2*)(pt + plane + o0);
    float2 tg1 = *(const float2*)(pt + plane + o1);
    float2 tb0 = *(const float2*)(pt + 2 * plane + o0);
    float2 tb1 = *(const float2*)(pt + 2 * plane + o1);

    float dr00 = ir0.x - tr0.x, dr01 = ir0.y - tr0.y;
    float dr10 = ir1.x - tr1.x, dr11 = ir1.y - tr1.y;
    float dg00 = ig0.x - tg0.x, dg01 = ig0.y - tg0.y;
    float dg10 = ig1.x - tg1.x, dg11 = ig1.y - tg1.y;
    float db00 = ib0.x - tb0.x, db01 = ib0.y - tb0.y;
    float db10 = ib1.x - tb1.x, db11 = ib1.y - tb1.y;

    sY0[8 + x0]     = 0.299f * dr00 + 0.587f * dg00 + 0.114f * db00;
    sY0[8 + x0 + 1] = 0.299f * dr01 + 0.587f * dg01 + 0.114f * db01;
    sY1[8 + x0]     = 0.299f * dr10 + 0.587f * dg10 + 0.114f * db10;
    sY1[8 + x0 + 1] = 0.299f * dr11 + 0.587f * dg11 + 0.114f * db11;

    float sr = dr00 + dr01 + dr10 + dr11;
    float sg = dg00 + dg01 + dg10 + dg11;
    float sb = db00 + db01 + db10 + db11;
    sU[8 + tid] = (-0.169f * sr - 0.331f * sg + 0.5f * sb) * 0.25f;
    sV[8 + tid] = ( 0.5f   * sr - 0.46f  * sg - 0.04f * sb) * 0.25f;

    __syncthreads();

    // --- hbox Y: each thread 4 consecutive outputs in one row (running sum) ---
    {
        const int row = tid >> 7;              // 0 or 1
        const int xb  = (tid & 127) << 2;      // 0..508
        const float* srow = row ? sY1 : sY0;
        float s = 0.f;
#pragma unroll
        for (int j = 1; j <= 15; ++j) s += srow[xb + j];
        ushort4 o;
        o.x = f2bf(s); s += srow[xb + 16] - srow[xb + 1];
        o.y = f2bf(s); s += srow[xb + 17] - srow[xb + 2];
        o.z = f2bf(s); s += srow[xb + 18] - srow[xb + 3];
        o.w = f2bf(s);
        *(ushort4*)(hY + ((size_t)n * H + y0 + row) * W + xb) = o;
    }

    // --- hbox chroma: threads 0-127 -> U, 128-255 -> V, 2 outputs each ---
    {
        const int uv = tid >> 7;
        const int t  = tid & 127;
        const int xb = t << 1;
        const float* srow = uv ? sV : sU;
        float s = 0.f;
#pragma unroll
        for (int j = 1; j <= 15; ++j) s += srow[xb + j];
        ushort2 o;
        o.x = f2bf(s); s += srow[xb + 16] - srow[xb + 1];
        o.y = f2bf(s);
        const size_t p = (size_t)(n * 2 + uv);
        *(ushort2*)(hUV + (p * CH + cy) * CW + xb) = o;
    }
}

// ---------------------------------------------------------------------------
// K2: massively-parallel vertical 15-tap box + square + block partial.
// One ushort2 (2 columns) per thread, 15 unrolled taps (clamp + select-zero).
// Blocks [0,8192): Y — block = (img, row), full 512-col row per block.
// Blocks [8192,12288): UV — q = plane*2^15 + y*128 + x2.
// NO same-address atomics (R1: 13 ns/atomic serialization).
// ---------------------------------------------------------------------------
#define K2_NBLK 12288
__global__ void vbox_sq_partial_kernel(const unsigned short* __restrict__ hY,
                                       const unsigned short* __restrict__ hUV,
                                       float invY, float invC,
                                       float* __restrict__ partials) {
    const int b = blockIdx.x;
    float val;
    if (b < 8192) {
        const int q  = b * 256 + threadIdx.x;      // [0, 2M)
        const int x2 = q & 255;                    // ushort2 index in row
        const int y  = (q >> 8) & (H - 1);
        const int img = q >> 17;
        const unsigned short* col = hY + ((size_t)img << 18) + (x2 << 1);
        float s0 = 0.f, s1 = 0.f;
#pragma unroll
        for (int t = -HALF; t <= HALF; ++t) {
            const int yy = y + t;
            const int yc = min(max(yy, 0), H - 1);
            const unsigned v = *(const unsigned*)(col + ((size_t)yc << 9));
            const bool in = (yy == yc);
            s0 += in ? bf2f((unsigned short)(v & 0xFFFFu)) : 0.f;
            s1 += in ? bf2f((unsigned short)(v >> 16)) : 0.f;
        }
        val = (s0 * s0 + s1 * s1) * invY;
    } else {
        const int q  = (b - 8192) * 256 + threadIdx.x;   // [0, 1M)
        const int x2 = q & 127;
        const int y  = (q >> 7) & (CH - 1);
        const int plane = q >> 15;
        const unsigned short* col = hUV + ((size_t)plane << 16) + (x2 << 1);
        float s0 = 0.f, s1 = 0.f;
#pragma unroll
        for (int t = -HALF; t <= HALF; ++t) {
            const int yy = y + t;
            const int yc = min(max(yy, 0), CH - 1);
            const unsigned v = *(const unsigned*)(col + ((size_t)yc << 8));
            const bool in = (yy == yc);
            s0 += in ? bf2f((unsigned short)(v & 0xFFFFu)) : 0.f;
            s1 += in ? bf2f((unsigned short)(v >> 16)) : 0.f;
        }
        val = (s0 * s0 + s1 * s1) * invC;
    }

    for (int o = 32; o > 0; o >>= 1) val += __shfl_down(val, o, 64);
    __shared__ float part[4];
    const int lane = threadIdx.x & 63, wid = threadIdx.x >> 6;
    if (lane == 0) part[wid] = val;
    __syncthreads();
    if (threadIdx.x == 0)
        partials[b] = (part[0] + part[1] + part[2] + part[3]);
}

// ---------------------------------------------------------------------------
// K3: single-block final sum of all partials -> out[0].
// ---------------------------------------------------------------------------
__global__ void final_reduce_kernel(const float* __restrict__ partials, int n,
                                    float* __restrict__ out) {
    float s = 0.f;
    for (int i = threadIdx.x; i < n; i += 1024) s += partials[i];
    for (int o = 32; o > 0; o >>= 1) s += __shfl_down(s, o, 64);
    __shared__ float part[16];
    const int lane = threadIdx.x & 63, wid = threadIdx.x >> 6;
    if (lane == 0) part[wid] = s;
    __syncthreads();
    if (threadIdx.x == 0) {
        float t = 0.f;
#pragma unroll
        for (int i = 0; i < 16; ++i) t += part[i];
        *out = t;
    }
}

extern "C" void kernel_launch(void* const* d_in, const int* in_sizes, int n_in,
                              void* d_out, int out_size, void* d_ws, size_t ws_size,
                              hipStream_t stream) {
    const float* input  = (const float*)d_in[0];
    const float* target = (const float*)d_in[1];
    float* out = (float*)d_out;

    const size_t yElems = (size_t)NIMG * H * W;      // 4,194,304
    const size_t cElems = (size_t)NIMG * CH * CW;    // 1,048,576

    unsigned short* hY  = (unsigned short*)d_ws;          // yElems bf16
    unsigned short* hUV = hY + yElems;                    // 2*cElems bf16
    float* partials = (float*)(hUV + 2 * cElems);         // K2_NBLK floats

    diff_hbox_kernel<<<NIMG * CH, 256, 0, stream>>>(input, target, hY, hUV);

    vbox_sq_partial_kernel<<<K2_NBLK, 256, 0, stream>>>(
        hY, hUV, 1.0f / (float)yElems, 1.0f / (float)cElems, partials);

    final_reduce_kernel<<<1, 1024, 0, stream>>>(partials, K2_NBLK, out);
}

// Round 6
// 130.563 us; speedup vs baseline: 1.3150x; 1.0405x over previous
//
#include <hip/hip_runtime.h>

#define NIMG 16
#define H 512
#define W 512
#define CH 256
#define CW 256
#define HALF 7   // PATCH=15

// bf16 helpers (RNE), bit-level.
static __device__ __forceinline__ unsigned short f2bf(float f) {
    unsigned u = __float_as_uint(f);
    u += 0x7FFFu + ((u >> 16) & 1u);
    return (unsigned short)(u >> 16);
}
static __device__ __forceinline__ float bf2f(unsigned short h) {
    return __uint_as_float(((unsigned)h) << 16);
}
static __device__ __forceinline__ float bflo(unsigned v) {
    return __uint_as_float(v << 16);
}
static __device__ __forceinline__ float bfhi(unsigned v) {
    return __uint_as_float(v & 0xFFFF0000u);
}

// ---------------------------------------------------------------------------
// K1: fused diff + horizontal 15-tap box. One block (256 thr) per (n, cy)
// full-res row pair. dY rows + pooled dU/dV row live only in LDS (zero-padded
// +-8: no clamping). Outputs hY (bf16, 8 MB) and hUV (bf16, 4 MB).
// Compulsory-read-bound: 128 MB in, 12 MB out. (Unchanged from R5 — passed.)
// ---------------------------------------------------------------------------
__global__ void diff_hbox_kernel(const float* __restrict__ in, const float* __restrict__ tgt,
                                 unsigned short* __restrict__ hY,
                                 unsigned short* __restrict__ hUV) {
    __shared__ float sY0[W + 16], sY1[W + 16], sU[CW + 16], sV[CW + 16];
    const int tid = threadIdx.x;
    const int cy = blockIdx.x & (CH - 1);
    const int n  = blockIdx.x >> 8;

    if (tid < 8) {
        sY0[tid] = 0.f; sY0[W + 8 + tid] = 0.f;
        sY1[tid] = 0.f; sY1[W + 8 + tid] = 0.f;
        sU[tid] = 0.f;  sU[CW + 8 + tid] = 0.f;
        sV[tid] = 0.f;  sV[CW + 8 + tid] = 0.f;
    }

    const size_t plane = (size_t)H * W;
    const float* pi = in  + (size_t)n * 3 * plane;
    const float* pt = tgt + (size_t)n * 3 * plane;

    const int y0 = cy << 1;
    const int x0 = tid << 1;
    const size_t o0 = (size_t)y0 * W + x0;
    const size_t o1 = o0 + W;

    float2 ir0 = *(const float2*)(pi + o0);
    float2 ir1 = *(const float2*)(pi + o1);
    float2 ig0 = *(const float2*)(pi + plane + o0);
    float2 ig1 = *(const float2*)(pi + plane + o1);
    float2 ib0 = *(const float2*)(pi + 2 * plane + o0);
    float2 ib1 = *(const float2*)(pi + 2 * plane + o1);

    float2 tr0 = *(const float2*)(pt + o0);
    float2 tr1 = *(const float2*)(pt + o1);
    float2 tg0 = *(const float2*)(pt + plane + o0);
    float2 tg1 = *(const float2*)(pt + plane + o1);
    float2 tb0 = *(const float2*)(pt + 2 * plane + o0);
    float2 tb1 = *(const float2*)(pt + 2 * plane + o1);

    float dr00 = ir0.x - tr0.x, dr01 = ir0.y - tr0.y;
    float dr10 = ir1.x - tr1.x, dr11 = ir1.y - tr1.y;
    float dg00 = ig0.x - tg0.x, dg01 = ig0.y - tg0.y;
    float dg10 = ig1.x - tg1.x, dg11 = ig1.y - tg1.y;
    float db00 = ib0.x - tb0.x, db01 = ib0.y - tb0.y;
    float db10 = ib1.x - tb1.x, db11 = ib1.y - tb1.y;

    sY0[8 + x0]     = 0.299f * dr00 + 0.587f * dg00 + 0.114f * db00;
    sY0[8 + x0 + 1] = 0.299f * dr01 + 0.587f * dg01 + 0.114f * db01;
    sY1[8 + x0]     = 0.299f * dr10 + 0.587f * dg10 + 0.114f * db10;
    sY1[8 + x0 + 1] = 0.299f * dr11 + 0.587f * dg11 + 0.114f * db11;

    float sr = dr00 + dr01 + dr10 + dr11;
    float sg = dg00 + dg01 + dg10 + dg11;
    float sb = db00 + db01 + db10 + db11;
    sU[8 + tid] = (-0.169f * sr - 0.331f * sg + 0.5f * sb) * 0.25f;
    sV[8 + tid] = ( 0.5f   * sr - 0.46f  * sg - 0.04f * sb) * 0.25f;

    __syncthreads();

    {
        const int row = tid >> 7;
        const int xb  = (tid & 127) << 2;
        const float* srow = row ? sY1 : sY0;
        float s = 0.f;
#pragma unroll
        for (int j = 1; j <= 15; ++j) s += srow[xb + j];
        ushort4 o;
        o.x = f2bf(s); s += srow[xb + 16] - srow[xb + 1];
        o.y = f2bf(s); s += srow[xb + 17] - srow[xb + 2];
        o.z = f2bf(s); s += srow[xb + 18] - srow[xb + 3];
        o.w = f2bf(s);
        *(ushort4*)(hY + ((size_t)n * H + y0 + row) * W + xb) = o;
    }

    {
        const int uv = tid >> 7;
        const int t  = tid & 127;
        const int xb = t << 1;
        const float* srow = uv ? sV : sU;
        float s = 0.f;
#pragma unroll
        for (int j = 1; j <= 15; ++j) s += srow[xb + j];
        ushort2 o;
        o.x = f2bf(s); s += srow[xb + 16] - srow[xb + 1];
        o.y = f2bf(s);
        const size_t p = (size_t)(n * 2 + uv);
        *(ushort2*)(hUV + (p * CH + cy) * CW + xb) = o;
    }
}

// ---------------------------------------------------------------------------
// K2: vertical 15-tap box + square + block partial, 16B (8 bf16 cols) per
// thread per tap. Blocks [0,2048): Y. Blocks [2048,3072): UV.
// NO same-address atomics (R1: ~13 ns/atomic serialization).
// ---------------------------------------------------------------------------
#define K2_NBLK 3072
__global__ void vbox_sq_partial_kernel(const unsigned short* __restrict__ hY,
                                       const unsigned short* __restrict__ hUV,
                                       float invY, float invC,
                                       float* __restrict__ partials) {
    const int b = blockIdx.x;
    float s0 = 0.f, s1 = 0.f, s2 = 0.f, s3 = 0.f;
    float s4 = 0.f, s5 = 0.f, s6 = 0.f, s7 = 0.f;
    float inv;
    if (b < 2048) {
        const int q  = b * 256 + threadIdx.x;       // [0, 512K)
        const int x8 = q & 63;                      // 8-col group in row
        const int y  = (q >> 6) & (H - 1);
        const int img = q >> 15;
        const unsigned short* col = hY + ((size_t)img << 18) + (x8 << 3);
#pragma unroll
        for (int t = -HALF; t <= HALF; ++t) {
            const int yy = y + t;
            const int yc = min(max(yy, 0), H - 1);
            const uint4 v = *(const uint4*)(col + ((size_t)yc << 9));
            const float m = (yy == yc) ? 1.f : 0.f;
            s0 += m * bflo(v.x); s1 += m * bfhi(v.x);
            s2 += m * bflo(v.y); s3 += m * bfhi(v.y);
            s4 += m * bflo(v.z); s5 += m * bfhi(v.z);
            s6 += m * bflo(v.w); s7 += m * bfhi(v.w);
        }
        inv = invY;
    } else {
        const int q  = (b - 2048) * 256 + threadIdx.x;   // [0, 256K)
        const int x8 = q & 31;
        const int y  = (q >> 5) & (CH - 1);
        const int plane = q >> 13;
        const unsigned short* col = hUV + ((size_t)plane << 16) + (x8 << 3);
#pragma unroll
        for (int t = -HALF; t <= HALF; ++t) {
            const int yy = y + t;
            const int yc = min(max(yy, 0), CH - 1);
            const uint4 v = *(const uint4*)(col + ((size_t)yc << 8));
            const float m = (yy == yc) ? 1.f : 0.f;
            s0 += m * bflo(v.x); s1 += m * bfhi(v.x);
            s2 += m * bflo(v.y); s3 += m * bfhi(v.y);
            s4 += m * bflo(v.z); s5 += m * bfhi(v.z);
            s6 += m * bflo(v.w); s7 += m * bfhi(v.w);
        }
        inv = invC;
    }
    float val = ((s0 * s0 + s1 * s1) + (s2 * s2 + s3 * s3) +
                 (s4 * s4 + s5 * s5) + (s6 * s6 + s7 * s7)) * inv;

    for (int o = 32; o > 0; o >>= 1) val += __shfl_down(val, o, 64);
    __shared__ float part[4];
    const int lane = threadIdx.x & 63, wid = threadIdx.x >> 6;
    if (lane == 0) part[wid] = val;
    __syncthreads();
    if (threadIdx.x == 0)
        partials[b] = part[0] + part[1] + part[2] + part[3];
}

// ---------------------------------------------------------------------------
// K3: single-block final sum of partials -> out[0].
// ---------------------------------------------------------------------------
__global__ void final_reduce_kernel(const float* __restrict__ partials, int n,
                                    float* __restrict__ out) {
    float s = 0.f;
    for (int i = threadIdx.x; i < n; i += 256) s += partials[i];
    for (int o = 32; o > 0; o >>= 1) s += __shfl_down(s, o, 64);
    __shared__ float part[4];
    const int lane = threadIdx.x & 63, wid = threadIdx.x >> 6;
    if (lane == 0) part[wid] = s;
    __syncthreads();
    if (threadIdx.x == 0)
        *out = part[0] + part[1] + part[2] + part[3];
}

extern "C" void kernel_launch(void* const* d_in, const int* in_sizes, int n_in,
                              void* d_out, int out_size, void* d_ws, size_t ws_size,
                              hipStream_t stream) {
    const float* input  = (const float*)d_in[0];
    const float* target = (const float*)d_in[1];
    float* out = (float*)d_out;

    const size_t yElems = (size_t)NIMG * H * W;      // 4,194,304
    const size_t cElems = (size_t)NIMG * CH * CW;    // 1,048,576

    unsigned short* hY  = (unsigned short*)d_ws;          // yElems bf16
    unsigned short* hUV = hY + yElems;                    // 2*cElems bf16
    float* partials = (float*)(hUV + 2 * cElems);         // K2_NBLK floats

    diff_hbox_kernel<<<NIMG * CH, 256, 0, stream>>>(input, target, hY, hUV);

    vbox_sq_partial_kernel<<<K2_NBLK, 256, 0, stream>>>(
        hY, hUV, 1.0f / (float)yElems, 1.0f / (float)cElems, partials);

    final_reduce_kernel<<<1, 256, 0, stream>>>(partials, K2_NBLK, out);
}